// Round 5
// baseline (549.497 us; speedup 1.0000x reference)
//
#include <hip/hip_runtime.h>
#include <hip/hip_bf16.h>

typedef __bf16 bf16_t;
typedef __bf16 bf16x8 __attribute__((ext_vector_type(8)));
typedef float  f32x4  __attribute__((ext_vector_type(4)));

#define DK 1024   // d_in  (K)
#define DN 1024   // d_out (N)
#define RNK 32
#define BM 128
#define BN 256
#define BK 64
#define NKT 16

// ---- Pass 1: W_eff = W + C @ V_r^T, bf16, FRAGMENT-MAJOR -------------------
// Element (o, d) lives at lane = (o&15) + ((d>>3)&3)*16, byte-within-lane e=d&7,
// fragment id (n16 = o>>4, kt = d>>6, ks = (d>>5)&1):
//   byte = (((n16*16 + kt)*2 + ks)*64 + lane)*16 + e*2
// so one MFMA B-fragment (64 lanes x 16B) is a CONTIGUOUS 1KB block -> the
// GEMM loads B straight to VGPRs with fully-coalesced global_load_dwordx4.
__global__ void weff_kernel(const float* __restrict__ W,
                            const float* __restrict__ Vr,
                            const float* __restrict__ C,
                            bf16_t* __restrict__ WeffF)
{
    const int o  = blockIdx.x;       // 0..1023 (d_out row)
    const int g  = threadIdx.x;      // 0..127  (8-wide d_in group)
    const int d0 = g * 8;

    f32x4 cv[8];
#pragma unroll
    for (int q = 0; q < 8; ++q) cv[q] = *(const f32x4*)(C + o * RNK + q * 4);

    const f32x4* wrow = (const f32x4*)(W + (size_t)o * DK + d0);
    f32x4 w0 = wrow[0], w1 = wrow[1];
    float acc[8];
#pragma unroll
    for (int e = 0; e < 4; ++e) { acc[e] = w0[e]; acc[4 + e] = w1[e]; }

#pragma unroll
    for (int e = 0; e < 8; ++e) {
        const f32x4* vre = (const f32x4*)(Vr + (size_t)(d0 + e) * RNK);
        float s = 0.f;
#pragma unroll
        for (int q = 0; q < 8; ++q) {
            f32x4 v = vre[q];
            s += cv[q][0] * v[0] + cv[q][1] * v[1] + cv[q][2] * v[2] + cv[q][3] * v[3];
        }
        acc[e] += s;
    }

    bf16x8 out;
#pragma unroll
    for (int e = 0; e < 8; ++e) out[e] = (bf16_t)acc[e];

    const int n16 = o >> 4, r = o & 15;
    const int kt = g >> 3, ks = (g >> 2) & 1, kk = g & 3;
    const size_t byte = (size_t)(((n16 * 16 + kt) * 2 + ks) * 64 + (r + kk * 16)) * 16;
    *(bf16x8*)((char*)WeffF + byte) = out;
}

// ---- Pass 2: 128x256 tile, 4 waves (1x4), wave-tile 128x64 -----------------
// A: fp32->bf16 reg-staged into XOR-swizzled LDS (shared by all 4 waves).
// B: direct global->VGPR from fragment-major Weff (L2-hot), half-tile
//    staggered prefetch. One barrier per K-tile, counted vmcnt(12).
__global__ __launch_bounds__(256, 2) void corrlin_gemm_kernel(
    const float* __restrict__ X, const bf16_t* __restrict__ WeffF,
    const float* __restrict__ bias, float* __restrict__ Out)
{
    __shared__ __align__(16) char smem[32768];
    char* Ab0 = smem;                // 16KB each (128 rows x 64 k x bf16)
    char* Ab1 = smem + 16384;

    const int tid = threadIdx.x;
    const int nwg = gridDim.x;       // 2048
    const int b0  = blockIdx.x;
    const int L   = (b0 & 7) * (nwg >> 3) + (b0 >> 3);   // XCD-bijective
    const int bm  = L >> 2;          // DN/BN == 4
    const int bn  = L & 3;
    const int m0  = bm * BM;

    const int lane = tid & 63;
    const int wn   = tid >> 6;       // 0..3 (wave = one 64-col slice)
    const int srow = tid >> 3;       // 0..31
    const int sseg = tid & 7;        // 0..7

    f32x4 acc[8][4] = {};            // wave-tile 128x64 = 8mf x 4nf
    f32x4 areg[8];                   // A(t+1) staging regs (single set)
    bf16x8 bks0[4], bks1[4];         // B fragments, per-ks single sets

    const char* WB = (const char*)WeffF;
    const int n16b = bn * 16 + wn * 4;
    const int laneb = lane * 16;

    auto loadB = [&](int kt, int ks, bf16x8* dst) {
#pragma unroll
        for (int nf = 0; nf < 4; ++nf)
            dst[nf] = *(const bf16x8*)(WB
                + (size_t)((n16b + nf) * 32 + kt * 2 + ks) * 1024 + laneb);
    };
    auto issueA = [&](int kt) {
#pragma unroll
        for (int i = 0; i < 4; ++i) {
            const float* pa = X + (size_t)(m0 + i * 32 + srow) * DK + kt * BK + sseg * 8;
            areg[i * 2]     = *(const f32x4*)pa;
            areg[i * 2 + 1] = *(const f32x4*)(pa + 4);
        }
    };
    auto storeA = [&](char* Ab) {
#pragma unroll
        for (int i = 0; i < 4; ++i) {
            const int row = i * 32 + srow;
            const int off = row * 128 + ((sseg * 16) ^ ((row & 7) << 4));
            bf16x8 v;
#pragma unroll
            for (int j = 0; j < 4; ++j) { v[j] = (bf16_t)areg[i * 2][j]; v[4 + j] = (bf16_t)areg[i * 2 + 1][j]; }
            *(bf16x8*)(Ab + off) = v;
        }
    };
    auto compute_ks = [&](const char* Ac, int ks, const bf16x8* bfr) {
        const int kb = ks * 64 + (lane >> 4) * 16;
#pragma unroll
        for (int h = 0; h < 2; ++h) {
            bf16x8 af[4];
#pragma unroll
            for (int i = 0; i < 4; ++i) {
                const int row = (h * 4 + i) * 16 + (lane & 15);
                af[i] = *(const bf16x8*)(Ac + row * 128 + (kb ^ ((row & 7) << 4)));
            }
            __builtin_amdgcn_s_setprio(1);
#pragma unroll
            for (int i = 0; i < 4; ++i)
#pragma unroll
                for (int nf = 0; nf < 4; ++nf)
                    acc[h * 4 + i][nf] = __builtin_amdgcn_mfma_f32_16x16x32_bf16(
                        af[i], bfr[nf], acc[h * 4 + i][nf], 0, 0, 0);
            __builtin_amdgcn_s_setprio(0);
        }
    };

    auto iter = [&](int t, const char* Ac, char* An) {
        compute_ks(Ac, 0, bks0);           // uses B(t).ks0
        if (t + 1 < NKT) loadB(t + 1, 0, bks0);   // refill (WAR ok: MFMAs issued)
        if (t + 1 < NKT) storeA(An);       // auto-waits A(t+1) regs only
        if (t + 2 < NKT) issueA(t + 2);    // stays in flight across barrier
        compute_ks(Ac, 1, bks1);           // uses B(t).ks1
        if (t + 1 < NKT) loadB(t + 1, 1, bks1);
        // end-of-iter: need B(t+1).ks0 drained; keep A(t+2) + B(t+1).ks1 flying
        if (t + 2 < NKT) {
            asm volatile("s_waitcnt vmcnt(12) lgkmcnt(0)" ::: "memory");
            __builtin_amdgcn_s_barrier();
        } else if (t + 1 < NKT) {
            asm volatile("s_waitcnt vmcnt(4) lgkmcnt(0)" ::: "memory");
            __builtin_amdgcn_s_barrier();
        }
    };

    // ---- prologue ----
    loadB(0, 0, bks0);
    loadB(0, 1, bks1);
    issueA(0);
    storeA(Ab0);                     // auto vmcnt(0): drains B(0) too (needed anyway)
    issueA(1);
    asm volatile("s_waitcnt lgkmcnt(0)" ::: "memory");
    __builtin_amdgcn_s_barrier();

    for (int t = 0; t < NKT; t += 2) {
        iter(t,     Ab0, Ab1);
        iter(t + 1, Ab1, Ab0);
    }
    __syncthreads();                 // LDS free for epilogue reuse

    // ---- epilogue: per-wave LDS transpose -> full-line f32x4 stores --------
    float* tb = (float*)smem + wn * 1280;   // 16 x 80 f32 per wave (20KB total)
    const int nbase = bn * BN + wn * 64;
    float bv[4];
#pragma unroll
    for (int nf = 0; nf < 4; ++nf) bv[nf] = bias[nbase + nf * 16 + (lane & 15)];

#pragma unroll
    for (int mf = 0; mf < 8; ++mf) {
#pragma unroll
        for (int nf = 0; nf < 4; ++nf)
#pragma unroll
            for (int j = 0; j < 4; ++j) {
                const int r = (lane >> 4) * 4 + j;
                const int c = nf * 16 + (lane & 15);
                tb[r * 80 + c] = acc[mf][nf][j] + bv[nf];
            }
        __syncthreads();
#pragma unroll
        for (int jj = 0; jj < 4; ++jj) {
            const int rr = jj * 4 + (lane >> 4);
            const int cc = (lane & 15) * 4;
            f32x4 v = *(const f32x4*)&tb[rr * 80 + cc];
            *(f32x4*)&Out[(size_t)(m0 + mf * 16 + rr) * DN + nbase + cc] = v;
        }
        __syncthreads();
    }
}

extern "C" void kernel_launch(void* const* d_in, const int* in_sizes, int n_in,
                              void* d_out, int out_size, void* d_ws, size_t ws_size,
                              hipStream_t stream) {
    const float* x  = (const float*)d_in[0];
    const float* W  = (const float*)d_in[1];
    const float* b  = (const float*)d_in[2];
    const float* Vr = (const float*)d_in[3];
    const float* C  = (const float*)d_in[4];
    float* out = (float*)d_out;

    const int M = in_sizes[0] / DK;            // 65536
    bf16_t* WeffF = (bf16_t*)d_ws;             // 2 MB fragment-major W_eff

    weff_kernel<<<DN, 128, 0, stream>>>(W, Vr, C, WeffF);

    const int mtiles = M / BM;                 // 512
    const int nwg = mtiles * (DN / BN);        // 2048
    corrlin_gemm_kernel<<<nwg, 256, 0, stream>>>(x, WeffF, b, out);
}

// Round 6
// 288.181 us; speedup vs baseline: 1.9068x; 1.9068x over previous
//
#include <hip/hip_runtime.h>
#include <hip/hip_bf16.h>

typedef __bf16 bf16_t;
typedef __bf16 bf16x8 __attribute__((ext_vector_type(8)));
typedef float  f32x4  __attribute__((ext_vector_type(4)));

#define DK 1024   // d_in  (K)
#define DN 1024   // d_out (N)
#define RNK 32
#define BM 256
#define BN 256
#define BK 64
#define NKT 16

// ---- Pass 1: W_eff = W + C @ V_r^T, bf16, PRE-SWIZZLED -------------------
// Chunks [bn(4)][kt(16)] of 32KB = exact LDS image of a 256row x 64k tile:
// byte(rloc,k) = rloc*128 + ((k*2) ^ ((rloc&7)<<4)). GEMM stages with linear
// global_load_lds (swizzle-on-source, linear dest).
__global__ void weff_kernel(const float* __restrict__ W,
                            const float* __restrict__ Vr,
                            const float* __restrict__ C,
                            bf16_t* __restrict__ WeffSw)
{
    const int o  = blockIdx.x;       // 0..1023 (d_out row)
    const int g  = threadIdx.x;      // 0..127  (8-wide d_in group)
    const int d0 = g * 8;

    f32x4 cv[8];
#pragma unroll
    for (int q = 0; q < 8; ++q) cv[q] = *(const f32x4*)(C + o * RNK + q * 4);

    const f32x4* wrow = (const f32x4*)(W + (size_t)o * DK + d0);
    f32x4 w0 = wrow[0], w1 = wrow[1];
    float acc[8];
#pragma unroll
    for (int e = 0; e < 4; ++e) { acc[e] = w0[e]; acc[4 + e] = w1[e]; }

#pragma unroll
    for (int e = 0; e < 8; ++e) {
        const f32x4* vre = (const f32x4*)(Vr + (size_t)(d0 + e) * RNK);
        float s = 0.f;
#pragma unroll
        for (int q = 0; q < 8; ++q) {
            f32x4 v = vre[q];
            s += cv[q][0] * v[0] + cv[q][1] * v[1] + cv[q][2] * v[2] + cv[q][3] * v[3];
        }
        acc[e] += s;
    }

    bf16x8 out;
#pragma unroll
    for (int e = 0; e < 8; ++e) out[e] = (bf16_t)acc[e];

    const int bn = o >> 8, rloc = o & 255;
    const int kt = g >> 3, kgrp = g & 7;
    const size_t byte = (size_t)(bn * 16 + kt) * 32768
                      + rloc * 128 + ((kgrp * 16) ^ ((rloc & 7) << 4));
    *(bf16x8*)((char*)WeffSw + byte) = out;
}

// ---- Pass 2: 256x256 tile, 8 waves (2Mx4N), 4-phase template schedule ----
// Stage ops spread across phases so every global load has >=3-phase lead:
//   P0: issueA.h1(t+1), issueB(t+1)   P2: writeA.h0(t+1)
//   P3: writeA.h1(t+1), issueA.h0(t+2), counted vmcnt(4)
__global__ __launch_bounds__(512, 2) void corrlin_gemm_kernel(
    const float* __restrict__ X, const bf16_t* __restrict__ WeffSw,
    const float* __restrict__ bias, float* __restrict__ Out)
{
    __shared__ __align__(16) char smem[131072];
    char* Abuf0 = smem;            // 32KB each
    char* Abuf1 = smem + 32768;
    char* Bbuf0 = smem + 65536;
    char* Bbuf1 = smem + 98304;

    const int tid = threadIdx.x;
    const int b0  = blockIdx.x;
    // XCD-bijective swizzle, nwg = 1024
    const int L  = (b0 & 7) * 128 + (b0 >> 3);
    const int bm = L >> 2;          // 256 m-tiles
    const int bn = L & 3;           // 4 n-tiles
    const int m0 = bm * BM;

    const int lane = tid & 63;
    const int wid  = tid >> 6;      // 0..7
    const int wm   = wid >> 2;      // 0..1
    const int wn   = wid & 3;       // 0..3

    const int arow = tid >> 1;            // 0..255
    const int ak0  = (tid & 1) * 32;      // float index within BK

    f32x4 acc[8][4] = {};
    f32x4 areg[8];

    const size_t bchunk0 = (size_t)bn * 16 * 32768;

    auto issueA_h = [&](int kt, int h) {
        const float* p = X + (size_t)(m0 + arow) * DK + kt * BK + ak0 + h * 16;
#pragma unroll
        for (int j = 0; j < 4; ++j) areg[h * 4 + j] = *(const f32x4*)(p + j * 4);
    };
    auto writeA_h = [&](char* Ab, int h) {
        const int rsw = (arow & 7) << 4;
#pragma unroll
        for (int w = h * 2; w < h * 2 + 2; ++w) {
            bf16x8 v;
#pragma unroll
            for (int e = 0; e < 4; ++e) { v[e] = (bf16_t)areg[w * 2][e]; v[4 + e] = (bf16_t)areg[w * 2 + 1][e]; }
            *(bf16x8*)(Ab + arow * 128 + ((ak0 * 2 + w * 16) ^ rsw)) = v;
        }
    };
    auto issueB = [&](int kt, char* Bb) {
        const char* g = (const char*)WeffSw + bchunk0 + (size_t)kt * 32768;
        const int lin = wid * 1024;
#pragma unroll
        for (int c = 0; c < 4; ++c) {
            __builtin_amdgcn_global_load_lds(
                (const __attribute__((address_space(1))) void*)(g + c * 8192 + lin + lane * 16),
                (__attribute__((address_space(3))) void*)(Bb + c * 8192 + lin),
                16, 0, 0);
        }
    };
    auto readA = [&](const char* Ab, int ks, int mfh, bf16x8* af) {
        const int kb = ks * 64 + (lane >> 4) * 16;
#pragma unroll
        for (int i = 0; i < 4; ++i) {
            const int row = wm * 128 + (mfh * 4 + i) * 16 + (lane & 15);
            af[i] = *(const bf16x8*)(Ab + row * 128 + (kb ^ ((row & 7) << 4)));
        }
    };
    auto readB = [&](const char* Bb, int ks, bf16x8* bfr) {
        const int kb = ks * 64 + (lane >> 4) * 16;
#pragma unroll
        for (int i = 0; i < 4; ++i) {
            const int row = wn * 64 + i * 16 + (lane & 15);
            bfr[i] = *(const bf16x8*)(Bb + row * 128 + (kb ^ ((row & 7) << 4)));
        }
    };
    auto mfma16 = [&](const bf16x8* af, const bf16x8* bfr, int mfh) {
        __builtin_amdgcn_s_setprio(1);
#pragma unroll
        for (int i = 0; i < 4; ++i)
#pragma unroll
            for (int nf = 0; nf < 4; ++nf)
                acc[mfh * 4 + i][nf] = __builtin_amdgcn_mfma_f32_16x16x32_bf16(
                    af[i], bfr[nf], acc[mfh * 4 + i][nf], 0, 0, 0);
        __builtin_amdgcn_s_setprio(0);
    };

    // ---- prologue: tile 0 staged, A(1).h0 in flight ----
    issueB(0, Bbuf0);
    issueA_h(0, 0); issueA_h(0, 1);
    writeA_h(Abuf0, 0); writeA_h(Abuf0, 1);  // auto vmcnt(0): drains B(0) too
    issueA_h(1, 0);
    asm volatile("s_waitcnt lgkmcnt(0)" ::: "memory");
    __builtin_amdgcn_s_barrier();

    for (int t = 0; t < NKT; ++t) {
        const char* Ac = (t & 1) ? Abuf1 : Abuf0;
        const char* Bc = (t & 1) ? Bbuf1 : Bbuf0;
        char* An = (t & 1) ? Abuf0 : Abuf1;
        char* Bn = (t & 1) ? Bbuf0 : Bbuf1;
        bf16x8 af[4], bfr[4];

        // P0: (ks0, mfh0) + issueA.h1(t+1) [before issueB: age order matters]
        readB(Bc, 0, bfr);
        readA(Ac, 0, 0, af);
        if (t + 1 < NKT) issueA_h(t + 1, 1);
        if (t + 1 < NKT) issueB(t + 1, Bn);
        __builtin_amdgcn_s_barrier();
        mfma16(af, bfr, 0);
        __builtin_amdgcn_s_barrier();

        // P1: (ks0, mfh1)
        readA(Ac, 0, 1, af);
        __builtin_amdgcn_s_barrier();
        mfma16(af, bfr, 1);
        __builtin_amdgcn_s_barrier();

        // P2: (ks1, mfh0) + writeA.h0(t+1)  [h0 regs issued P3 of t-1: 3-phase lead]
        readB(Bc, 1, bfr);
        readA(Ac, 1, 0, af);
        if (t + 1 < NKT) writeA_h(An, 0);
        __builtin_amdgcn_s_barrier();
        mfma16(af, bfr, 0);
        __builtin_amdgcn_s_barrier();

        // P3: (ks1, mfh1) + writeA.h1(t+1) + issueA.h0(t+2) + counted vmcnt
        readA(Ac, 1, 1, af);
        if (t + 1 < NKT) writeA_h(An, 1);     // waits A(t+1).h1 (P0, 3-phase lead)
        if (t + 2 < NKT) issueA_h(t + 2, 0);  // refills areg[0..3] after P2 read them
        __builtin_amdgcn_s_barrier();
        mfma16(af, bfr, 1);
        if (t + 1 < NKT) {
            if (t + 2 < NKT) asm volatile("s_waitcnt vmcnt(4) lgkmcnt(0)" ::: "memory");  // drain B(t+1), keep A(t+2).h0
            else             asm volatile("s_waitcnt vmcnt(0) lgkmcnt(0)" ::: "memory");
        }
        __builtin_amdgcn_s_barrier();
    }

    // ---- epilogue: per-wave LDS transpose -> full-line f32x4 stores ----
    __syncthreads();
    float* tb = (float*)smem + wid * 1280;   // 16 x 80 f32 per wave
    const int mbase = m0 + wm * 128;
    const int nbase = bn * BN + wn * 64;
    float bv[4];
#pragma unroll
    for (int nf = 0; nf < 4; ++nf) bv[nf] = bias[nbase + nf * 16 + (lane & 15)];

#pragma unroll
    for (int mf = 0; mf < 8; ++mf) {
#pragma unroll
        for (int nf = 0; nf < 4; ++nf)
#pragma unroll
            for (int j = 0; j < 4; ++j) {
                const int r = (lane >> 4) * 4 + j;
                const int c = nf * 16 + (lane & 15);
                tb[r * 80 + c] = acc[mf][nf][j] + bv[nf];
            }
        __syncthreads();
#pragma unroll
        for (int jj = 0; jj < 4; ++jj) {
            const int rr = jj * 4 + (lane >> 4);
            const int cc = (lane & 15) * 4;
            f32x4 v = *(const f32x4*)&tb[rr * 80 + cc];
            *(f32x4*)&Out[(size_t)(mbase + mf * 16 + rr) * DN + nbase + cc] = v;
        }
        __syncthreads();
    }
}

extern "C" void kernel_launch(void* const* d_in, const int* in_sizes, int n_in,
                              void* d_out, int out_size, void* d_ws, size_t ws_size,
                              hipStream_t stream) {
    const float* x  = (const float*)d_in[0];
    const float* W  = (const float*)d_in[1];
    const float* b  = (const float*)d_in[2];
    const float* Vr = (const float*)d_in[3];
    const float* C  = (const float*)d_in[4];
    float* out = (float*)d_out;

    const int M = in_sizes[0] / DK;            // 65536
    bf16_t* WeffSw = (bf16_t*)d_ws;            // 2 MB pre-swizzled W_eff

    weff_kernel<<<DN, 128, 0, stream>>>(W, Vr, C, WeffSw);

    const int mtiles = M / BM;                 // 256
    const int nwg = mtiles * (DN / BN);        // 1024
    corrlin_gemm_kernel<<<nwg, 512, 0, stream>>>(x, WeffSw, b, out);
}

// Round 7
// 204.275 us; speedup vs baseline: 2.6900x; 1.4108x over previous
//
#include <hip/hip_runtime.h>
#include <hip/hip_bf16.h>

typedef __bf16 bf16_t;
typedef __bf16 bf16x8 __attribute__((ext_vector_type(8)));
typedef float  f32x4  __attribute__((ext_vector_type(4)));

#define DK 1024   // d_in  (K)
#define DN 1024   // d_out (N)
#define RNK 32
#define BM 128
#define BN 512
#define BK 32
#define NKT 32

// ---- Pass 1: W_eff = W + C @ V_r^T, bf16, PRE-SWIZZLED ---------------------
// Chunks [bn(2)][kt(32)] of 32KB = exact LDS image of a 512row x 32k tile.
// Element (rloc, kloc): byte = rloc*64 + ((seg ^ ((rloc>>1)&3))<<4) + (kloc&7)*2
// with seg = kloc>>3. Rows 0..7 map to 8 distinct 16B slots per 128B window
// -> conflict-free ds_read_b128. GEMM stages with linear global_load_lds.
__global__ void weff_kernel(const float* __restrict__ W,
                            const float* __restrict__ Vr,
                            const float* __restrict__ C,
                            bf16_t* __restrict__ WeffSw)
{
    const int o  = blockIdx.x;       // 0..1023 (d_out row)
    const int g  = threadIdx.x;      // 0..127  (8-wide d_in group)
    const int d0 = g * 8;

    f32x4 cv[8];
#pragma unroll
    for (int q = 0; q < 8; ++q) cv[q] = *(const f32x4*)(C + o * RNK + q * 4);

    const f32x4* wrow = (const f32x4*)(W + (size_t)o * DK + d0);
    f32x4 w0 = wrow[0], w1 = wrow[1];
    float acc[8];
#pragma unroll
    for (int e = 0; e < 4; ++e) { acc[e] = w0[e]; acc[4 + e] = w1[e]; }

#pragma unroll
    for (int e = 0; e < 8; ++e) {
        const f32x4* vre = (const f32x4*)(Vr + (size_t)(d0 + e) * RNK);
        float s = 0.f;
#pragma unroll
        for (int q = 0; q < 8; ++q) {
            f32x4 v = vre[q];
            s += cv[q][0] * v[0] + cv[q][1] * v[1] + cv[q][2] * v[2] + cv[q][3] * v[3];
        }
        acc[e] += s;
    }

    bf16x8 out;
#pragma unroll
    for (int e = 0; e < 8; ++e) out[e] = (bf16_t)acc[e];

    const int bn = o >> 9, rloc = o & 511;
    const int kt = d0 >> 5, seg = (d0 >> 3) & 3;
    const int sw = seg ^ ((rloc >> 1) & 3);
    const size_t byte = (size_t)(bn * 32 + kt) * 32768 + rloc * 64 + (sw << 4);
    *(bf16x8*)((char*)WeffSw + byte) = out;
}

// ---- Pass 2: 128x512 tile, BK=32, 8 waves each 128x64, 1 barrier/iter ------
// BN=512 cuts fp32-x traffic to ~1000 cyc/K-step/CU (< MFMA 1241) -- removes
// the x-bandwidth wall that capped BN<=256 variants at 20-22% MfmaUtil.
__global__ __launch_bounds__(512, 1) void corrlin_gemm_kernel(
    const float* __restrict__ X, const bf16_t* __restrict__ WeffSw,
    const float* __restrict__ bias, float* __restrict__ Out)
{
    __shared__ __align__(16) char smem[81920];
    char* Ab0 = smem;                 // 8KB each (128 rows x 32 k bf16)
    char* Ab1 = smem + 8192;
    char* Bb0 = smem + 16384;         // 32KB each (512 rows x 32 k bf16)
    char* Bb1 = smem + 49152;

    const int tid = threadIdx.x;
    const int b0  = blockIdx.x;
    // XCD-bijective swizzle, nwg = 1024; bn-pair of one x-panel adjacent
    const int L  = (b0 & 7) * 128 + (b0 >> 3);
    const int bm = L >> 1;            // 512 m-tiles
    const int bn = L & 1;             // 2 n-tiles
    const int m0 = bm * BM;

    const int lane = tid & 63;
    const int wn   = tid >> 6;        // 0..7: wave's 64-col slice
    const int arow = tid >> 2;        // 0..127
    const int aseg = tid & 3;         // 0..3 (16B chunk within 64B row)

    f32x4 acc[8][4] = {};
    f32x4 set0[2], set1[2];           // depth-2 A prefetch (named sets, rule #20)

    auto issueA = [&](int kt, f32x4* s) {
        const float* p = X + (size_t)(m0 + arow) * DK + kt * BK + aseg * 8;
        s[0] = *(const f32x4*)p;
        s[1] = *(const f32x4*)(p + 4);
    };
    auto storeA = [&](const f32x4* s, char* Ab) {
        const int sw = aseg ^ ((arow >> 1) & 3);
        bf16x8 v;
#pragma unroll
        for (int j = 0; j < 4; ++j) { v[j] = (bf16_t)s[0][j]; v[4 + j] = (bf16_t)s[1][j]; }
        *(bf16x8*)(Ab + arow * 64 + (sw << 4)) = v;
    };
    auto issueB = [&](int kt, char* Bb) {
        const char* g = (const char*)WeffSw + (size_t)(bn * 32 + kt) * 32768;
#pragma unroll
        for (int c = 0; c < 4; ++c) {
            const int lin = c * 8192 + wn * 1024;        // wave-uniform dest
            __builtin_amdgcn_global_load_lds(
                (const __attribute__((address_space(1))) void*)(g + lin + lane * 16),
                (__attribute__((address_space(3))) void*)(Bb + lin),
                16, 0, 0);
        }
    };
    auto readB = [&](const char* Bc, bf16x8* bfr) {
        const int kb = lane >> 4;     // 0..3
#pragma unroll
        for (int nf = 0; nf < 4; ++nf) {
            const int row = wn * 64 + nf * 16 + (lane & 15);
            bfr[nf] = *(const bf16x8*)(Bc + row * 64 + ((kb ^ ((row >> 1) & 3)) << 4));
        }
    };
    auto compute_h = [&](const char* Ac, int h, const bf16x8* bfr) {
        bf16x8 af[4];
        const int kb = lane >> 4;
#pragma unroll
        for (int i = 0; i < 4; ++i) {
            const int row = (h * 4 + i) * 16 + (lane & 15);
            af[i] = *(const bf16x8*)(Ac + row * 64 + ((kb ^ ((row >> 1) & 3)) << 4));
        }
        __builtin_amdgcn_s_setprio(1);
#pragma unroll
        for (int i = 0; i < 4; ++i)
#pragma unroll
            for (int nf = 0; nf < 4; ++nf)
                acc[h * 4 + i][nf] = __builtin_amdgcn_mfma_f32_16x16x32_bf16(
                    af[i], bfr[nf], acc[h * 4 + i][nf], 0, 0, 0);
        __builtin_amdgcn_s_setprio(0);
    };

    auto iter = [&](int t, const char* Ac, const char* Bc, char* An, char* Bn,
                    f32x4* aStore /*holds A(t+1)*/, f32x4* aFill /*gets A(t+2)*/) {
        if (t + 1 < NKT) issueB(t + 1, Bn);   // oldest VMEM this iter
        bf16x8 bfr[4];
        readB(Bc, bfr);
        compute_h(Ac, 0, bfr);
        if (t + 1 < NKT) storeA(aStore, An);  // auto-waits A(t+1) regs only
        if (t + 2 < NKT) issueA(t + 2, aFill);
        compute_h(Ac, 1, bfr);
        if (t + 2 < NKT) {
            asm volatile("s_waitcnt vmcnt(2) lgkmcnt(0)" ::: "memory");  // drain B(t+1), keep A(t+2)
            __builtin_amdgcn_s_barrier();
        } else if (t + 1 < NKT) {
            asm volatile("s_waitcnt vmcnt(0) lgkmcnt(0)" ::: "memory");
            __builtin_amdgcn_s_barrier();
        }
    };

    // ---- prologue: A(0)->LDS, A(1) in regs, B(0) staged ----
    issueA(0, set0);
    issueB(0, Bb0);
    storeA(set0, Ab0);               // auto-waits A(0)
    issueA(1, set1);
    asm volatile("s_waitcnt vmcnt(2) lgkmcnt(0)" ::: "memory");  // B(0) done, A(1) flying
    __builtin_amdgcn_s_barrier();

    for (int t = 0; t < NKT; t += 2) {
        iter(t,     Ab0, Bb0, Ab1, Bb1, set1, set0);
        iter(t + 1, Ab1, Bb1, Ab0, Bb0, set0, set1);
    }
    __syncthreads();                 // LDS free for epilogue reuse

    // ---- epilogue: per-wave LDS transpose -> full-line f32x4 stores --------
    float* tb = (float*)smem + wn * 1280;    // 16 x 80 f32 per wave (40KB)
    const int nbase = bn * BN + wn * 64;
    float bv[4];
#pragma unroll
    for (int nf = 0; nf < 4; ++nf) bv[nf] = bias[nbase + nf * 16 + (lane & 15)];

#pragma unroll
    for (int mf = 0; mf < 8; ++mf) {
#pragma unroll
        for (int nf = 0; nf < 4; ++nf)
#pragma unroll
            for (int j = 0; j < 4; ++j) {
                const int r = (lane >> 4) * 4 + j;
                const int c = nf * 16 + (lane & 15);
                tb[r * 80 + c] = acc[mf][nf][j] + bv[nf];
            }
        __syncthreads();
#pragma unroll
        for (int jj = 0; jj < 4; ++jj) {
            const int rr = jj * 4 + (lane >> 4);
            const int cc = (lane & 15) * 4;
            f32x4 v = *(const f32x4*)&tb[rr * 80 + cc];
            *(f32x4*)&Out[(size_t)(m0 + mf * 16 + rr) * DN + nbase + cc] = v;
        }
        __syncthreads();
    }
}

extern "C" void kernel_launch(void* const* d_in, const int* in_sizes, int n_in,
                              void* d_out, int out_size, void* d_ws, size_t ws_size,
                              hipStream_t stream) {
    const float* x  = (const float*)d_in[0];
    const float* W  = (const float*)d_in[1];
    const float* b  = (const float*)d_in[2];
    const float* Vr = (const float*)d_in[3];
    const float* C  = (const float*)d_in[4];
    float* out = (float*)d_out;

    const int M = in_sizes[0] / DK;            // 65536
    bf16_t* WeffSw = (bf16_t*)d_ws;            // 2 MB pre-swizzled W_eff

    weff_kernel<<<DN, 128, 0, stream>>>(W, Vr, C, WeffSw);

    const int mtiles = M / BM;                 // 512
    const int nwg = mtiles * (DN / BN);        // 1024
    corrlin_gemm_kernel<<<nwg, 512, 0, stream>>>(x, WeffSw, b, out);
}